// Round 18
// baseline (61175.287 us; speedup 1.0000x reference)
//
#include <hip/hip_runtime.h>
#include <hip/hip_bf16.h>
#include <stdint.h>

constexpr int kSEQ = 8192;
constexpr int kIN  = 1024;
constexpr int kH   = 2048;
constexpr int kG4  = 4 * kH;   // 8192 gate rows
constexpr int kNB  = 256;      // persistent workgroups (1 per CU)
constexpr int kHB  = kH / kNB; // 8 h-values owned per WG
constexpr int kWP  = kH + 16;  // LDS weight row stride

// ---- workspace layout (bytes) ----
constexpr size_t OFF_HBUF  = 0;          // u64 hbuf[2][kH]  (32 KB) tagged h words
constexpr size_t OFF_ABORT = 32768;      // uint32 abort flag
constexpr size_t OFF_HS    = 65536;      // bf16 hs[kSEQ][kH]   (32 MB)
constexpr size_t OFF_XP    = OFF_HS + (size_t)kSEQ * kH * 2; // bf16 xp[kSEQ][kG4] (128 MB)

typedef unsigned int uint4v __attribute__((ext_vector_type(4)));
typedef __attribute__((ext_vector_type(8))) short bf16x8;
typedef __attribute__((ext_vector_type(4))) float f32x4;

__device__ __forceinline__ float bflo(uint32_t v) { return __uint_as_float(v << 16); }
__device__ __forceinline__ float bfhi(uint32_t v) { return __uint_as_float(v & 0xffff0000u); }

// ---------------------------------------------------------------------------
// Kernel 1 (MFMA, R17-proven): x_proj = input.W_ih^T + b_ih + b_hh
// 128x128 C-tile, 4 waves as 2x2 of 64x64, mfma_f32_16x16x32_bf16, K-tile 32.
// ---------------------------------------------------------------------------
__global__ __launch_bounds__(256) void k_xproj(const float* __restrict__ A,
                                               const float* __restrict__ B,
                                               const float* __restrict__ bih,
                                               const float* __restrict__ bhh,
                                               __hip_bfloat16* __restrict__ C)
{
    constexpr int LDR = 40;   // bf16 units per LDS row (padded)
    __shared__ __hip_bfloat16 Al[128 * LDR];
    __shared__ __hip_bfloat16 Bl[128 * LDR];

    const int tid = threadIdx.x;
    const int bx  = blockIdx.x & 63;   // n tile
    const int by  = blockIdx.x >> 6;   // m tile
    const int m0  = by * 128, n0 = bx * 128;
    const int w   = tid >> 6;
    const int l   = tid & 63;
    const int wm  = w >> 1, wn = w & 1;    // 2x2 wave grid of 64x64
    const int fr  = l & 15, fg = l >> 4;   // fragment row / k-group

    f32x4 acc[4][4] = {};                  // [fm][fn]

    const int sr = tid >> 1;               // staging row 0..127
    const int sh = (tid & 1) << 4;         // k offset 0 / 16

    for (int k0 = 0; k0 < kIN; k0 += 32) {
        const float* as = A + (size_t)(m0 + sr) * kIN + k0 + sh;
        const float* bs = B + (size_t)(n0 + sr) * kIN + k0 + sh;
        float4 a0 = *(const float4*)(as);
        float4 a1 = *(const float4*)(as + 4);
        float4 a2 = *(const float4*)(as + 8);
        float4 a3 = *(const float4*)(as + 12);
        float4 b0 = *(const float4*)(bs);
        float4 b1 = *(const float4*)(bs + 4);
        float4 b2 = *(const float4*)(bs + 8);
        float4 b3 = *(const float4*)(bs + 12);
        __syncthreads();   // protect previous iteration's fragment reads
        {
            __hip_bfloat16* ad = Al + sr * LDR + sh;
            __hip_bfloat16* bd = Bl + sr * LDR + sh;
            ad[0]=__float2bfloat16(a0.x);  ad[1]=__float2bfloat16(a0.y);
            ad[2]=__float2bfloat16(a0.z);  ad[3]=__float2bfloat16(a0.w);
            ad[4]=__float2bfloat16(a1.x);  ad[5]=__float2bfloat16(a1.y);
            ad[6]=__float2bfloat16(a1.z);  ad[7]=__float2bfloat16(a1.w);
            ad[8]=__float2bfloat16(a2.x);  ad[9]=__float2bfloat16(a2.y);
            ad[10]=__float2bfloat16(a2.z); ad[11]=__float2bfloat16(a2.w);
            ad[12]=__float2bfloat16(a3.x); ad[13]=__float2bfloat16(a3.y);
            ad[14]=__float2bfloat16(a3.z); ad[15]=__float2bfloat16(a3.w);
            bd[0]=__float2bfloat16(b0.x);  bd[1]=__float2bfloat16(b0.y);
            bd[2]=__float2bfloat16(b0.z);  bd[3]=__float2bfloat16(b0.w);
            bd[4]=__float2bfloat16(b1.x);  bd[5]=__float2bfloat16(b1.y);
            bd[6]=__float2bfloat16(b1.z);  bd[7]=__float2bfloat16(b1.w);
            bd[8]=__float2bfloat16(b2.x);  bd[9]=__float2bfloat16(b2.y);
            bd[10]=__float2bfloat16(b2.z); bd[11]=__float2bfloat16(b2.w);
            bd[12]=__float2bfloat16(b3.x); bd[13]=__float2bfloat16(b3.y);
            bd[14]=__float2bfloat16(b3.z); bd[15]=__float2bfloat16(b3.w);
        }
        __syncthreads();

        bf16x8 am[4], bn[4];
        #pragma unroll
        for (int f = 0; f < 4; ++f) {
            am[f] = *(const bf16x8*)(Al + (wm * 64 + f * 16 + fr) * LDR + fg * 8);
            bn[f] = *(const bf16x8*)(Bl + (wn * 64 + f * 16 + fr) * LDR + fg * 8);
        }
        #pragma unroll
        for (int fm = 0; fm < 4; ++fm)
            #pragma unroll
            for (int fn = 0; fn < 4; ++fn)
                acc[fm][fn] = __builtin_amdgcn_mfma_f32_16x16x32_bf16(
                                  am[fm], bn[fn], acc[fm][fn], 0, 0, 0);
    }

    // epilogue: D row=(l>>4)*4+r, col=l&15 ; add bias, store bf16
    #pragma unroll
    for (int fn = 0; fn < 4; ++fn) {
        const int cn = n0 + wn * 64 + fn * 16 + fr;
        const float bb = bih[cn] + bhh[cn];
        #pragma unroll
        for (int fm = 0; fm < 4; ++fm) {
            const int rbase = m0 + wm * 64 + fm * 16 + fg * 4;
            #pragma unroll
            for (int r = 0; r < 4; ++r)
                C[(size_t)(rbase + r) * kG4 + cn] = __float2bfloat16(acc[fm][fn][r] + bb);
        }
    }
}

// ---------------------------------------------------------------------------
// Kernel 2 (R18): persistent LSTM recurrence, 256 WGs x 512 threads (8 waves).
// Same proven family as R16: 1-hop data-carrying tagged sync, coherent
// dwordx4 poll sweep, single barrier/step, straight-line matvec.
// Widened: wave w owns h index hb+w (all 4 gates). Lane group l>>4 = gate
// row; 16 lanes x 16 iters x 8 MACs = 128 MACs/thread (half of R16).
// Staging/poll: 4 words/thread -> 2 x 16B coherent loads (sweep op count
// chip-wide unchanged). Weight LDS row = h_local*4 + gate, stride kWP.
// ---------------------------------------------------------------------------
__global__ __launch_bounds__(512, 1) void k_lstm(const float* __restrict__ Whh,
                                                 const __hip_bfloat16* __restrict__ xp,
                                                 unsigned long long* __restrict__ hbuf, // [2][kH]
                                                 uint32_t* __restrict__ abortf,
                                                 __hip_bfloat16* __restrict__ hs)
{
    extern __shared__ char smem[];
    __hip_bfloat16* Wl  = (__hip_bfloat16*)smem;              // [32][kWP] bf16
    float*          hl2 = (float*)(smem + 32 * kWP * 2);      // [2][kH] fp32

    const int wg  = blockIdx.x;
    const int tid = threadIdx.x;
    const int w   = tid >> 6;   // wave id 0..7 == h-local index
    const int l   = tid & 63;
    const int hb  = wg * kHB;

    // ---- one-time: stage W_hh slice; LDS row lr = h_local*4 + gate ----
    {
        const int lr = tid >> 4;             // 0..31
        const int g  = lr & 3;               // gate
        const int jl = lr >> 2;              // h-local 0..7
        const int cb = (tid & 15) * 128;
        const float* src = Whh + (size_t)(g * kH + hb + jl) * kH + cb;
        __hip_bfloat16* dst = Wl + (size_t)lr * kWP + cb;
        for (int c = 0; c < 128; c += 4) {
            float4 v = *(const float4*)(src + c);
            dst[c + 0] = __float2bfloat16(v.x);
            dst[c + 1] = __float2bfloat16(v.y);
            dst[c + 2] = __float2bfloat16(v.z);
            dst[c + 3] = __float2bfloat16(v.w);
        }
    }
    __syncthreads();

    const __hip_bfloat16* wrow = Wl + (size_t)(w * 4 + (l >> 4)) * kWP; // gate row
    const int kbase = (l & 15) * 8;
    const int jg = hb + w;                    // this wave's h index (global)
    float c_state = 0.0f;
    uint32_t budget = 0;                      // whole-kernel retry budget

    for (int t = 0; t < kSEQ; ++t) {
        // ---- issue this wave's 4 x_proj gate values early (retire under poll) ----
        const __hip_bfloat16* xr = xp + (size_t)t * kG4 + jg;
        const float xi = __bfloat162float(xr[0]);
        const float xf = __bfloat162float(xr[kH]);
        const float xg = __bfloat162float(xr[2 * kH]);
        const float xo = __bfloat162float(xr[3 * kH]);

        // ---- gather h_{t-1} into hl2[t&1]: 32B/thread coherent sweep ----
        float* hw = hl2 + (size_t)(t & 1) * kH + tid * 4;
        int dead = 0;
        if (t == 0) {
            hw[0] = 0.f; hw[1] = 0.f; hw[2] = 0.f; hw[3] = 0.f;
        } else {
            const unsigned long long* src = hbuf + (size_t)((t - 1) & 1) * kH + tid * 4;
            const uint32_t tag = (uint32_t)t;
            uint4v q0, q1;
            for (;;) {
                asm volatile(
                    "global_load_dwordx4 %0, %2, off sc0 sc1\n\t"
                    "global_load_dwordx4 %1, %2, off offset:16 sc0 sc1\n\t"
                    "s_waitcnt vmcnt(0)"
                    : "=&v"(q0), "=&v"(q1)
                    : "v"(src)
                    : "memory");
                bool ok = (q0[0] == tag) & (q0[2] == tag) & (q1[0] == tag) & (q1[2] == tag);
                if (ok) break;
                if ((++budget & 15) == 0) {
                    if (__hip_atomic_load(abortf, __ATOMIC_RELAXED,
                                          __HIP_MEMORY_SCOPE_AGENT) != 0u) { dead = 1; break; }
                    if (budget > (1u << 21)) { dead = 1; break; }
                }
            }
            hw[0] = __uint_as_float(q0[1]); hw[1] = __uint_as_float(q0[3]);
            hw[2] = __uint_as_float(q1[1]); hw[3] = __uint_as_float(q1[3]);
        }
        if (__syncthreads_or(dead)) {   // single barrier/step; uniform exit
            __hip_atomic_store(abortf, 1u, __ATOMIC_RELAXED, __HIP_MEMORY_SCOPE_AGENT);
            return;
        }

        // ---- matvec: gate row l>>4; 16 lanes cover k; 16 iters x 8 MACs ----
        const float* hv = hl2 + (size_t)(t & 1) * kH;
        float acc = 0.f;
        #pragma unroll 8
        for (int it = 0; it < 16; ++it) {
            const int k = it * 128 + kbase;
            uint4 wv = *(const uint4*)(wrow + k);
            float4 h0 = *(const float4*)(hv + k);
            float4 h1 = *(const float4*)(hv + k + 4);
            acc += bflo(wv.x) * h0.x + bfhi(wv.x) * h0.y
                 + bflo(wv.y) * h0.z + bfhi(wv.y) * h0.w
                 + bflo(wv.z) * h1.x + bfhi(wv.z) * h1.y
                 + bflo(wv.w) * h1.z + bfhi(wv.w) * h1.w;
        }
        acc += __shfl_xor(acc, 1);
        acc += __shfl_xor(acc, 2);
        acc += __shfl_xor(acc, 4);
        acc += __shfl_xor(acc, 8);   // all 16 lanes of each gate group hold the sum

        // ---- gates live at lanes 0/16/32/48; broadcast, update, publish ----
        const float gi = __shfl(acc, 0)  + xi;
        const float gf = __shfl(acc, 16) + xf;
        const float gg = __shfl(acc, 32) + xg;
        const float go = __shfl(acc, 48) + xo;
        const float si = 1.f / (1.f + expf(-gi));
        const float sf = 1.f / (1.f + expf(-gf));
        const float tg = tanhf(gg);
        const float so = 1.f / (1.f + expf(-go));
        c_state = sf * c_state + si * tg;            // replicated per wave
        const float hvv = so * tanhf(c_state);
        if (l == 0) {
            hs[(size_t)t * kH + jg] = __float2bfloat16(hvv);
            const unsigned long long pv =
                ((unsigned long long)__float_as_uint(hvv) << 32) | (uint32_t)(t + 1);
            __hip_atomic_store(hbuf + (size_t)(t & 1) * kH + jg, pv,
                               __ATOMIC_RELAXED, __HIP_MEMORY_SCOPE_AGENT);
        }
        // no trailing barrier: tags + next step's single barrier self-synchronize
    }
}

// ---------------------------------------------------------------------------
// Kernel 3: out[t] = sigmoid(hs[t] . W_lin + b_lin). One wave per t.
// ---------------------------------------------------------------------------
__global__ __launch_bounds__(256) void k_out(const __hip_bfloat16* __restrict__ hs,
                                             const float* __restrict__ wlin,
                                             const float* __restrict__ blin,
                                             float* __restrict__ out)
{
    const int w = threadIdx.x >> 6, l = threadIdx.x & 63;
    const int t = blockIdx.x * 4 + w;
    const __hip_bfloat16* row = hs + (size_t)t * kH;
    float acc = 0.f;
    #pragma unroll
    for (int i = 0; i < 4; ++i) {
        const int k = i * 512 + l * 8;
        uint4 hv = *(const uint4*)(row + k);
        float4 w0 = *(const float4*)(wlin + k);
        float4 w1 = *(const float4*)(wlin + k + 4);
        acc += bflo(hv.x) * w0.x + bfhi(hv.x) * w0.y
             + bflo(hv.y) * w0.z + bfhi(hv.y) * w0.w
             + bflo(hv.z) * w1.x + bfhi(hv.z) * w1.y
             + bflo(hv.w) * w1.z + bfhi(hv.w) * w1.w;
    }
    #pragma unroll
    for (int s = 32; s >= 1; s >>= 1) acc += __shfl_xor(acc, s);
    if (l == 0) out[t] = 1.f / (1.f + expf(-(acc + blin[0])));
}

// ---------------------------------------------------------------------------
extern "C" void kernel_launch(void* const* d_in, const int* in_sizes, int n_in,
                              void* d_out, int out_size, void* d_ws, size_t ws_size,
                              hipStream_t stream)
{
    const float* input_seq = (const float*)d_in[0];
    const float* W_ih      = (const float*)d_in[1];
    const float* W_hh      = (const float*)d_in[2];
    const float* b_ih      = (const float*)d_in[3];
    const float* b_hh      = (const float*)d_in[4];
    const float* W_lin     = (const float*)d_in[5];
    const float* b_lin     = (const float*)d_in[6];
    float* out = (float*)d_out;
    char*  ws  = (char*)d_ws;

    unsigned long long* hbuf = (unsigned long long*)(ws + OFF_HBUF);
    uint32_t*           abf  = (uint32_t*)(ws + OFF_ABORT);
    __hip_bfloat16*     hs   = (__hip_bfloat16*)(ws + OFF_HS);
    __hip_bfloat16*     xpb  = (__hip_bfloat16*)(ws + OFF_XP);

    // zero hbuf tags + abort each call (harness does not re-poison between replays)
    hipMemsetAsync(ws, 0, 65536, stream);

    k_xproj<<<dim3(64 * 64), dim3(256), 0, stream>>>(input_seq, W_ih, b_ih, b_hh, xpb);

    constexpr int kLds = 32 * kWP * 2 + 2 * kH * 4;   // 148480 B
    hipFuncSetAttribute((const void*)k_lstm, hipFuncAttributeMaxDynamicSharedMemorySize, kLds);

    // Preferred: cooperative launch -> driver guarantees all 256 WGs co-resident,
    // so the tag-poll is provably live. Fallback: plain launch (whole-kernel
    // bounded spin + sticky abort still prevents any hang).
    {
        const float* a0 = W_hh; const __hip_bfloat16* a1 = xpb;
        unsigned long long* a2 = hbuf; uint32_t* a3 = abf; __hip_bfloat16* a4 = hs;
        void* args[5] = { &a0, &a1, &a2, &a3, &a4 };
        hipError_t ce = hipLaunchCooperativeKernel((const void*)k_lstm, dim3(kNB), dim3(512),
                                                   args, (unsigned)kLds, stream);
        if (ce != hipSuccess) {
            k_lstm<<<dim3(kNB), dim3(512), kLds, stream>>>(W_hh, xpb, hbuf, abf, hs);
        }
    }

    k_out<<<dim3(kSEQ / 4), dim3(256), 0, stream>>>(hs, W_lin, b_lin, out);
}